// Round 3
// baseline (637.712 us; speedup 1.0000x reference)
//
#include <hip/hip_runtime.h>
#include <hip/hip_bf16.h>
#include <cstdint>
#include <cstddef>

// Problem constants (fixed shapes)
#define Bn   4
#define Sn   4096
#define Nn   16384
#define CSn  256
#define COn  128
#define CINn 384
#define MTOT 65536   // B*N

using short8 = short __attribute__((ext_vector_type(8)));
using f32x4  = float __attribute__((ext_vector_type(4)));

static __device__ __forceinline__ float bf2f(unsigned short u){
  unsigned int x = ((unsigned int)u) << 16;
  return __builtin_bit_cast(float, x);
}
static __device__ __forceinline__ unsigned short f2bf(float f){
  unsigned int x = __builtin_bit_cast(unsigned int, f);
  x += 0x7fffu + ((x >> 16) & 1u);   // RNE (no NaN handling needed; data finite)
  return (unsigned short)(x >> 16);
}

// ---------------- KNN ----------------
static __device__ __forceinline__ void top3_insert(float d, int s,
    float& d0, float& d1, float& d2, int& i0, int& i1, int& i2){
  if (d < d2){
    if (d < d1){
      d2 = d1; i2 = i1;
      if (d < d0){ d1 = d0; i1 = i0; d0 = d; i0 = s; }
      else       { d1 = d;  i1 = s; }
    } else { d2 = d; i2 = s; }
  }
}

// precompute sampled keys (x,y,z,||s||^2) to global — L2 resident (64KB/batch)
__global__ __launch_bounds__(256) void skey_kernel(
    const float* __restrict__ sxyz, float4* __restrict__ skey)
{
  const int i = blockIdx.x*256 + threadIdx.x;      // 0 .. B*Sn-1
  float x = sxyz[(size_t)i*3+0], y = sxyz[(size_t)i*3+1], z = sxyz[(size_t)i*3+2];
  float ssv = __fadd_rn(__fadd_rn(__fmul_rn(x,x), __fmul_rn(y,y)), __fmul_rn(z,z));
  skey[i] = make_float4(x, y, z, ssv);
}

// 1024 blocks x 512 threads (8 waves). Block = 64 queries (lane = query),
// wave w scans S-slice [w*512, w*512+512). Slice base offset is routed through
// an opaque v_mov so the loads stay VMEM (per-lane broadcast, L2-resident) with
// deep vmcnt pipelining instead of SGPR-starved s_loads.
// Distance form matches reference: (||q||^2 + ||s||^2) - 2*(q.s).
__global__ __launch_bounds__(512) void knn_kernel(
    const float4* __restrict__ skey, const float* __restrict__ oxyz,
    float* __restrict__ kw, int* __restrict__ ki)
{
  __shared__ float md[8][64][3];
  __shared__ int   mi[8][64][3];
  const int b      = blockIdx.x >> 8;      // 256 blocks per batch
  const int qgrp   = blockIdx.x & 255;
  const int lane   = threadIdx.x & 63;
  const int wave   = threadIdx.x >> 6;     // 0..7 = S-slice
  const int n      = qgrp*64 + lane;
  const float* op = oxyz + ((size_t)b*Nn + n)*3;
  const float px = op[0], py = op[1], pz = op[2];
  const float qq = __fadd_rn(__fadd_rn(__fmul_rn(px,px), __fmul_rn(py,py)), __fmul_rn(pz,pz));

  const int sbase = wave << 9;             // slice start in [0,4096)
  uint32_t off0 = (uint32_t)(((size_t)b*Sn + sbase) * sizeof(float4));
  uint32_t voff;
  asm volatile("v_mov_b32 %0, %1" : "=v"(voff) : "v"(off0));  // opaque: force VMEM
  const char* skb = (const char*)skey;

  float d0 = 3.4e38f, d1 = 3.4e38f, d2 = 3.4e38f;
  int   i0 = 0, i1 = 0, i2 = 0;
  #pragma unroll 8
  for (int s = 0; s < 512; ++s){
    float4 kv = *reinterpret_cast<const float4*>(skb + voff + (size_t)s*16);
    float dot = __fmaf_rn(pz, kv.z, __fmaf_rn(py, kv.y, __fmul_rn(px, kv.x)));
    float d   = __fmaf_rn(-2.0f, dot, __fadd_rn(qq, kv.w));
    top3_insert(d, sbase + s, d0, d1, d2, i0, i1, i2);
  }
  md[wave][lane][0]=d0; md[wave][lane][1]=d1; md[wave][lane][2]=d2;
  mi[wave][lane][0]=i0; mi[wave][lane][1]=i1; mi[wave][lane][2]=i2;
  __syncthreads();
  if (threadIdx.x < 64){
    float e0=3.4e38f, e1=3.4e38f, e2=3.4e38f;
    int   j0=0, j1=0, j2=0;
    // merge slices in ascending order; strict '<' keeps earlier index on ties
    #pragma unroll
    for (int w = 0; w < 8; ++w){
      top3_insert(md[w][lane][0], mi[w][lane][0], e0,e1,e2, j0,j1,j2);
      top3_insert(md[w][lane][1], mi[w][lane][1], e0,e1,e2, j0,j1,j2);
      top3_insert(md[w][lane][2], mi[w][lane][2], e0,e1,e2, j0,j1,j2);
    }
    float wa = 1.0f/(e0+1e-8f), wb = 1.0f/(e1+1e-8f), wc = 1.0f/(e2+1e-8f);
    float s  = __fadd_rn(__fadd_rn(wa, wb), wc);
    size_t base = ((size_t)b*Nn + n)*3;
    kw[base+0] = wa/s; kw[base+1] = wb/s; kw[base+2] = wc/s;
    ki[base+0] = j0;   ki[base+1] = j1;   ki[base+2] = j2;
  }
}

// ------------- interpolate + concat -> x [M][384] bf16 -------------
__global__ __launch_bounds__(256) void interp_kernel(
    const float* __restrict__ sfeat, const float* __restrict__ ofeat,
    const float* __restrict__ kw, const int* __restrict__ ki,
    unsigned short* __restrict__ X)
{
  const int c  = threadIdx.x;          // channel 0..255
  const int m0 = blockIdx.x * 16;      // 16 points per block
  for (int p = 0; p < 16; ++p){
    const int m = m0 + p;
    const int b = m >> 14;             // N = 16384
    const float w0v = kw[(size_t)m*3+0], w1v = kw[(size_t)m*3+1], w2v = kw[(size_t)m*3+2];
    const int   i0  = ki[(size_t)m*3+0], i1  = ki[(size_t)m*3+1], i2  = ki[(size_t)m*3+2];
    const float* sb = sfeat + (size_t)b * Sn * CSn;
    float v = __fmaf_rn(w2v, sb[(size_t)i2*CSn + c],
              __fmaf_rn(w1v, sb[(size_t)i1*CSn + c],
              __fmul_rn(w0v, sb[(size_t)i0*CSn + c])));
    X[(size_t)m*CINn + COn + c] = f2bf(v);
    if (c < COn) X[(size_t)m*CINn + c] = f2bf(ofeat[(size_t)m*COn + c]);
  }
}

// ------------- fp32 -> bf16 weight conversion -------------
__global__ __launch_bounds__(256) void cvtw_kernel(
    const float* __restrict__ w0, const float* __restrict__ w1,
    unsigned short* __restrict__ w0b, unsigned short* __restrict__ w1b)
{
  int i = blockIdx.x*256 + threadIdx.x;
  if (i < 256*384) w0b[i] = f2bf(w0[i]);
  int j = i - 256*384;
  if (j >= 0 && j < 256*256) w1b[j] = f2bf(w1[j]);
}

// ------------- GEMM: Y[M][256] = A[M][KDIM] @ W[256][KDIM]^T + bias ----------
// BM=128, BN=256 (full), BK=64. 4 waves, wave w owns cols [w*64, w*64+64).
// Optional prologue: A' = relu(A*scale[k] + shift[k]) (BN0+ReLU fused into GEMM1).
// Epilogue: bf16 store + per-channel sum/sumsq atomics for BN stats.
template<int KDIM, bool BNRELU>
__global__ __launch_bounds__(256) void gemm_kernel(
    const unsigned short* __restrict__ A,
    const unsigned short* __restrict__ W,
    const float* __restrict__ bias,
    const float* __restrict__ bnscale,
    const float* __restrict__ bnshift,
    unsigned short* __restrict__ Y,
    float* __restrict__ osum,
    float* __restrict__ osq)
{
  __shared__ unsigned short As[128*64];   // 16 KB, XOR-swizzled 16B chunks
  __shared__ unsigned short Bs[256*64];   // 32 KB
  __shared__ float lsc[256], lsh[256];
  const int tid  = threadIdx.x;
  const int lane = tid & 63;
  const int wave = tid >> 6;
  const size_t mbase = (size_t)blockIdx.x * 128;
  if constexpr (BNRELU){ lsc[tid] = bnscale[tid]; lsh[tid] = bnshift[tid]; }
  f32x4 acc[8][4];
  #pragma unroll
  for (int m2 = 0; m2 < 8; ++m2)
    #pragma unroll
    for (int n2 = 0; n2 < 4; ++n2) acc[m2][n2] = f32x4{0.f,0.f,0.f,0.f};
  __syncthreads();

  for (int k0 = 0; k0 < KDIM; k0 += 64){
    if (k0) __syncthreads();
    // stage A: 128 rows x 8 chunks(16B) = 1024 chunks, 4/thread
    #pragma unroll
    for (int i = 0; i < 4; ++i){
      int cid = tid + 256*i;
      int row = cid >> 3, c8 = cid & 7;
      short8 v = *reinterpret_cast<const short8*>(A + (mbase+row)*KDIM + k0 + c8*8);
      if constexpr (BNRELU){
        #pragma unroll
        for (int j = 0; j < 8; ++j){
          int kc = k0 + c8*8 + j;
          float f = bf2f((unsigned short)v[j]);
          f = fmaxf(__fmaf_rn(f, lsc[kc], lsh[kc]), 0.0f);
          v[j] = (short)f2bf(f);
        }
      }
      *reinterpret_cast<short8*>(reinterpret_cast<char*>(As) + row*128 + ((c8 ^ (row&7)) << 4)) = v;
    }
    // stage B (weights): 256 rows x 8 chunks = 2048 chunks, 8/thread
    #pragma unroll
    for (int i = 0; i < 8; ++i){
      int cid = tid + 256*i;
      int row = cid >> 3, c8 = cid & 7;
      short8 v = *reinterpret_cast<const short8*>(W + (size_t)row*KDIM + k0 + c8*8);
      *reinterpret_cast<short8*>(reinterpret_cast<char*>(Bs) + row*128 + ((c8 ^ (row&7)) << 4)) = v;
    }
    __syncthreads();
    #pragma unroll
    for (int kk = 0; kk < 2; ++kk){
      short8 af[8], bv[4];
      #pragma unroll
      for (int m2 = 0; m2 < 8; ++m2){
        int row = m2*16 + (lane & 15);
        int c8  = kk*4 + (lane >> 4);
        af[m2] = *reinterpret_cast<const short8*>(reinterpret_cast<char*>(As) + row*128 + ((c8 ^ (row&7)) << 4));
      }
      #pragma unroll
      for (int n2 = 0; n2 < 4; ++n2){
        int row = wave*64 + n2*16 + (lane & 15);
        int c8  = kk*4 + (lane >> 4);
        bv[n2] = *reinterpret_cast<const short8*>(reinterpret_cast<char*>(Bs) + row*128 + ((c8 ^ (row&7)) << 4));
      }
      #pragma unroll
      for (int m2 = 0; m2 < 8; ++m2)
        #pragma unroll
        for (int n2 = 0; n2 < 4; ++n2)
          acc[m2][n2] = __builtin_amdgcn_mfma_f32_16x16x32_bf16(af[m2], bv[n2], acc[m2][n2], 0, 0, 0);
    }
  }

  // epilogue: C/D layout col = lane&15, row = (lane>>4)*4 + j  [m89-verified]
  const int colg0 = wave*64;
  float spart[4] = {0,0,0,0}, qpart[4] = {0,0,0,0};
  #pragma unroll
  for (int m2 = 0; m2 < 8; ++m2){
    #pragma unroll
    for (int n2 = 0; n2 < 4; ++n2){
      const int gc  = colg0 + n2*16 + (lane & 15);
      const float bvv = bias[gc];
      #pragma unroll
      for (int j = 0; j < 4; ++j){
        float yv = acc[m2][n2][j] + bvv;
        size_t gr = mbase + m2*16 + (lane>>4)*4 + j;
        Y[gr*256 + gc] = f2bf(yv);
        spart[n2] += yv;
        qpart[n2] = __fmaf_rn(yv, yv, qpart[n2]);
      }
    }
  }
  #pragma unroll
  for (int n2 = 0; n2 < 4; ++n2){
    float s = spart[n2], q = qpart[n2];
    s += __shfl_xor(s, 16); q += __shfl_xor(q, 16);
    s += __shfl_xor(s, 32); q += __shfl_xor(q, 32);
    if (lane < 16){
      int gc = colg0 + n2*16 + lane;
      atomicAdd(&osum[gc], s);
      atomicAdd(&osq[gc], q);
    }
  }
}

// ------------- BN finalize: scale/shift from sums -------------
__global__ void bnfin_kernel(const float* __restrict__ ss, const float* __restrict__ sq,
    const float* __restrict__ g, const float* __restrict__ bt,
    float* __restrict__ sc, float* __restrict__ sh)
{
  int c = threadIdx.x;
  float mean = ss[c] * (1.0f/65536.0f);
  float var  = sq[c] * (1.0f/65536.0f) - mean*mean;   // biased (torch default)
  float s = g[c] / sqrtf(var + 1e-5f);
  sc[c] = s;
  sh[c] = __fmaf_rn(-mean, s, bt[c]);
}

// ------------- final BN1 + ReLU -> fp32 out -------------
__global__ __launch_bounds__(256) void apply_kernel(
    const unsigned short* __restrict__ y,
    const float* __restrict__ sc, const float* __restrict__ sh,
    float* __restrict__ out)
{
  const int t = blockIdx.x*256 + threadIdx.x;
  const size_t base = (size_t)t * 8;
  const int c0 = (int)(base & 255);
  short8 v = *reinterpret_cast<const short8*>(y + base);
  float r[8];
  #pragma unroll
  for (int j = 0; j < 8; ++j){
    float f = bf2f((unsigned short)v[j]);
    f = __fmaf_rn(f, sc[c0+j], sh[c0+j]);
    r[j] = fmaxf(f, 0.0f);
  }
  float4 o0, o1;
  o0.x=r[0]; o0.y=r[1]; o0.z=r[2]; o0.w=r[3];
  o1.x=r[4]; o1.y=r[5]; o1.z=r[6]; o1.w=r[7];
  *reinterpret_cast<float4*>(out + base)     = o0;
  *reinterpret_cast<float4*>(out + base + 4) = o1;
}

// ---------------- workspace layout ----------------
constexpr size_t WS_STATS = 0;                                  // 4*256 f32
constexpr size_t WS_SCALE = 4096;                               // 4*256 f32
constexpr size_t WS_W0B   = 8192;                               // 98304 bf16
constexpr size_t WS_W1B   = WS_W0B + 196608;                    // 65536 bf16
constexpr size_t WS_KW    = WS_W1B + 131072;                    // M*3 f32
constexpr size_t WS_KI    = WS_KW + 786432;                     // M*3 i32
constexpr size_t WS_SKEY  = WS_KI + 786432;                     // B*Sn float4 (256KB)
constexpr size_t WS_X     = 4194304;                            // M*384 bf16 (50.3 MB)
constexpr size_t WS_Y0    = WS_X + (size_t)MTOT*CINn*2;         // M*256 bf16 (33.5 MB)
// Y1 reuses the X region (X dead after GEMM0). Peak ws ~ 88 MB.

extern "C" void kernel_launch(void* const* d_in, const int* in_sizes, int n_in,
                              void* d_out, int out_size, void* d_ws, size_t ws_size,
                              hipStream_t stream)
{
  const float* sxyz  = (const float*)d_in[0];
  const float* sfeat = (const float*)d_in[1];
  const float* oxyz  = (const float*)d_in[2];
  const float* ofeat = (const float*)d_in[3];
  const float* w0    = (const float*)d_in[4];
  const float* b0    = (const float*)d_in[5];
  const float* g0    = (const float*)d_in[6];
  const float* bt0   = (const float*)d_in[7];
  const float* w1    = (const float*)d_in[8];
  const float* b1    = (const float*)d_in[9];
  const float* g1    = (const float*)d_in[10];
  const float* bt1   = (const float*)d_in[11];
  // d_in[12] = k (always 3, hard-coded)

  char* ws = (char*)d_ws;
  float* stats  = (float*)(ws + WS_STATS);   // sum0,ssq0,sum1,ssq1
  float* scales = (float*)(ws + WS_SCALE);   // scale0,shift0,scale1,shift1
  unsigned short* w0b = (unsigned short*)(ws + WS_W0B);
  unsigned short* w1b = (unsigned short*)(ws + WS_W1B);
  float* kw = (float*)(ws + WS_KW);
  int*   ki = (int*)(ws + WS_KI);
  float4* skey = (float4*)(ws + WS_SKEY);
  unsigned short* X  = (unsigned short*)(ws + WS_X);
  unsigned short* Y0 = (unsigned short*)(ws + WS_Y0);
  unsigned short* Y1 = (unsigned short*)(ws + WS_X);   // reuse

  hipMemsetAsync(stats, 0, 4*256*sizeof(float), stream);
  cvtw_kernel<<<640, 256, 0, stream>>>(w0, w1, w0b, w1b);
  skey_kernel<<<(Bn*Sn)/256, 256, 0, stream>>>(sxyz, skey);
  knn_kernel<<<1024, 512, 0, stream>>>(skey, oxyz, kw, ki);
  interp_kernel<<<MTOT/16, 256, 0, stream>>>(sfeat, ofeat, kw, ki, X);
  gemm_kernel<CINn, false><<<MTOT/128, 256, 0, stream>>>(
      X, w0b, b0, nullptr, nullptr, Y0, stats, stats + 256);
  bnfin_kernel<<<1, 256, 0, stream>>>(stats, stats + 256, g0, bt0, scales, scales + 256);
  gemm_kernel<256, true><<<MTOT/128, 256, 0, stream>>>(
      Y0, w1b, b1, scales, scales + 256, Y1, stats + 512, stats + 768);
  bnfin_kernel<<<1, 256, 0, stream>>>(stats + 512, stats + 768, g1, bt1, scales + 512, scales + 768);
  apply_kernel<<<(MTOT*256)/(256*8), 256, 0, stream>>>(Y1, scales + 512, scales + 768, (float*)d_out);
}

// Round 4
// 540.945 us; speedup vs baseline: 1.1789x; 1.1789x over previous
//
#include <hip/hip_runtime.h>
#include <hip/hip_bf16.h>
#include <cstdint>
#include <cstddef>

// Problem constants (fixed shapes)
#define Bn   4
#define Sn   4096
#define Nn   16384
#define CSn  256
#define COn  128
#define CINn 384
#define MTOT 65536   // B*N

using short8 = short __attribute__((ext_vector_type(8)));
using f32x4  = float __attribute__((ext_vector_type(4)));

static __device__ __forceinline__ float bf2f(unsigned short u){
  unsigned int x = ((unsigned int)u) << 16;
  return __builtin_bit_cast(float, x);
}
static __device__ __forceinline__ unsigned short f2bf(float f){
  unsigned int x = __builtin_bit_cast(unsigned int, f);
  x += 0x7fffu + ((x >> 16) & 1u);   // RNE (no NaN handling needed; data finite)
  return (unsigned short)(x >> 16);
}

// ---------------- KNN ----------------
static __device__ __forceinline__ void top3_insert(float d, int s,
    float& d0, float& d1, float& d2, int& i0, int& i1, int& i2){
  if (d < d2){
    if (d < d1){
      d2 = d1; i2 = i1;
      if (d < d0){ d1 = d0; i1 = i0; d0 = d; i0 = s; }
      else       { d1 = d;  i1 = s; }
    } else { d2 = d; i2 = s; }
  }
}

// precompute sampled keys (x,y,z,||s||^2) to global — L2 resident (64KB/batch)
__global__ __launch_bounds__(256) void skey_kernel(
    const float* __restrict__ sxyz, float4* __restrict__ skey)
{
  const int i = blockIdx.x*256 + threadIdx.x;      // 0 .. B*Sn-1
  float x = sxyz[(size_t)i*3+0], y = sxyz[(size_t)i*3+1], z = sxyz[(size_t)i*3+2];
  float ssv = __fadd_rn(__fadd_rn(__fmul_rn(x,x), __fmul_rn(y,y)), __fmul_rn(z,z));
  skey[i] = make_float4(x, y, z, ssv);
}

// 512 blocks x 512 threads (8 waves). Block = 128 queries; each thread owns
// Q=2 queries (lane, lane+64) -> 2 independent insert chains (ILP) and 2x
// reuse per loaded key. Wave w scans S-slice [w*512,(w+1)*512) via a
// wave-uniform pointer (readfirstlane) -> keys live in SGPRs (s_load_dwordx16),
// explicitly software-pipelined 4 points ahead. Dist ops read 1 SGPR each.
// Distance form matches reference: fma(-2, q.s, ||q||^2 + ||s||^2).
// Merge: ascending slice order, strict '<' => top_k tie-break preserved.
__global__ __launch_bounds__(512) void knn_kernel(
    const float4* __restrict__ skey, const float* __restrict__ oxyz,
    float* __restrict__ kw, int* __restrict__ ki)
{
  __shared__ float md[8][128][3];
  __shared__ int   mi[8][128][3];
  const int b     = blockIdx.x >> 7;      // 128 blocks per batch
  const int qblk  = blockIdx.x & 127;
  const int lane  = threadIdx.x & 63;
  const int wave  = threadIdx.x >> 6;     // 0..7 = S-slice
  const int n0    = qblk*128 + lane;      // query 0
  const int n1    = n0 + 64;              // query 1
  const float* op0 = oxyz + ((size_t)b*Nn + n0)*3;
  const float* op1 = oxyz + ((size_t)b*Nn + n1)*3;
  const float px0 = op0[0], py0 = op0[1], pz0 = op0[2];
  const float px1 = op1[0], py1 = op1[1], pz1 = op1[2];
  const float qq0 = __fadd_rn(__fadd_rn(__fmul_rn(px0,px0), __fmul_rn(py0,py0)), __fmul_rn(pz0,pz0));
  const float qq1 = __fadd_rn(__fadd_rn(__fmul_rn(px1,px1), __fmul_rn(py1,py1)), __fmul_rn(pz1,pz1));

  const int sbase = __builtin_amdgcn_readfirstlane(wave << 9);  // slice start
  const float4* sk = skey + (size_t)b*Sn + sbase;               // uniform -> s_load

  float a0 = 3.4e38f, a1 = 3.4e38f, a2 = 3.4e38f;   // top3 for q0
  int   x0 = 0, x1 = 0, x2 = 0;
  float b0_ = 3.4e38f, b1_ = 3.4e38f, b2_ = 3.4e38f; // top3 for q1
  int   y0 = 0, y1 = 0, y2 = 0;

  auto proc = [&](float4 kv, int sidx){
    float dot0 = __fmaf_rn(pz0, kv.z, __fmaf_rn(py0, kv.y, __fmul_rn(px0, kv.x)));
    float D0   = __fmaf_rn(-2.0f, dot0, __fadd_rn(qq0, kv.w));
    top3_insert(D0, sidx, a0, a1, a2, x0, x1, x2);
    float dot1 = __fmaf_rn(pz1, kv.z, __fmaf_rn(py1, kv.y, __fmul_rn(px1, kv.x)));
    float D1   = __fmaf_rn(-2.0f, dot1, __fadd_rn(qq1, kv.w));
    top3_insert(D1, sidx, b0_, b1_, b2_, y0, y1, y2);
  };

  float4 c0 = sk[0], c1 = sk[1], c2 = sk[2], c3 = sk[3];
  int s = 0;
  for (; s < 508; s += 4){
    float4 nx0 = sk[s+4], nx1 = sk[s+5], nx2 = sk[s+6], nx3 = sk[s+7];
    proc(c0, sbase+s); proc(c1, sbase+s+1); proc(c2, sbase+s+2); proc(c3, sbase+s+3);
    c0 = nx0; c1 = nx1; c2 = nx2; c3 = nx3;
  }
  proc(c0, sbase+508); proc(c1, sbase+509); proc(c2, sbase+510); proc(c3, sbase+511);

  md[wave][lane][0]=a0;  md[wave][lane][1]=a1;  md[wave][lane][2]=a2;
  mi[wave][lane][0]=x0;  mi[wave][lane][1]=x1;  mi[wave][lane][2]=x2;
  md[wave][64+lane][0]=b0_; md[wave][64+lane][1]=b1_; md[wave][64+lane][2]=b2_;
  mi[wave][64+lane][0]=y0;  mi[wave][64+lane][1]=y1;  mi[wave][64+lane][2]=y2;
  __syncthreads();
  if (threadIdx.x < 128){
    const int q = threadIdx.x;           // local query 0..127
    float e0=3.4e38f, e1=3.4e38f, e2=3.4e38f;
    int   j0=0, j1=0, j2=0;
    #pragma unroll
    for (int w = 0; w < 8; ++w){
      top3_insert(md[w][q][0], mi[w][q][0], e0,e1,e2, j0,j1,j2);
      top3_insert(md[w][q][1], mi[w][q][1], e0,e1,e2, j0,j1,j2);
      top3_insert(md[w][q][2], mi[w][q][2], e0,e1,e2, j0,j1,j2);
    }
    float wa = 1.0f/(e0+1e-8f), wb = 1.0f/(e1+1e-8f), wc = 1.0f/(e2+1e-8f);
    float sm = __fadd_rn(__fadd_rn(wa, wb), wc);
    size_t base = ((size_t)b*Nn + qblk*128 + q)*3;
    kw[base+0] = wa/sm; kw[base+1] = wb/sm; kw[base+2] = wc/sm;
    ki[base+0] = j0;    ki[base+1] = j1;    ki[base+2] = j2;
  }
}

// ------------- interpolate + concat -> x [M][384] bf16 -------------
__global__ __launch_bounds__(256) void interp_kernel(
    const float* __restrict__ sfeat, const float* __restrict__ ofeat,
    const float* __restrict__ kw, const int* __restrict__ ki,
    unsigned short* __restrict__ X)
{
  const int c  = threadIdx.x;          // channel 0..255
  const int m0 = blockIdx.x * 16;      // 16 points per block
  for (int p = 0; p < 16; ++p){
    const int m = m0 + p;
    const int b = m >> 14;             // N = 16384
    const float w0v = kw[(size_t)m*3+0], w1v = kw[(size_t)m*3+1], w2v = kw[(size_t)m*3+2];
    const int   i0  = ki[(size_t)m*3+0], i1  = ki[(size_t)m*3+1], i2  = ki[(size_t)m*3+2];
    const float* sb = sfeat + (size_t)b * Sn * CSn;
    float v = __fmaf_rn(w2v, sb[(size_t)i2*CSn + c],
              __fmaf_rn(w1v, sb[(size_t)i1*CSn + c],
              __fmul_rn(w0v, sb[(size_t)i0*CSn + c])));
    X[(size_t)m*CINn + COn + c] = f2bf(v);
    if (c < COn) X[(size_t)m*CINn + c] = f2bf(ofeat[(size_t)m*COn + c]);
  }
}

// ------------- fp32 -> bf16 weight conversion -------------
__global__ __launch_bounds__(256) void cvtw_kernel(
    const float* __restrict__ w0, const float* __restrict__ w1,
    unsigned short* __restrict__ w0b, unsigned short* __restrict__ w1b)
{
  int i = blockIdx.x*256 + threadIdx.x;
  if (i < 256*384) w0b[i] = f2bf(w0[i]);
  int j = i - 256*384;
  if (j >= 0 && j < 256*256) w1b[j] = f2bf(w1[j]);
}

// ------------- GEMM: Y[M][256] = A[M][KDIM] @ W[256][KDIM]^T + bias ----------
// BM=128, BN=256 (full), BK=64. 4 waves, wave w owns cols [w*64, w*64+64).
// Optional prologue: A' = relu(A*scale[k] + shift[k]) (BN0+ReLU fused into GEMM1).
// Epilogue: bf16 store + per-channel sum/sumsq atomics for BN stats.
template<int KDIM, bool BNRELU>
__global__ __launch_bounds__(256) void gemm_kernel(
    const unsigned short* __restrict__ A,
    const unsigned short* __restrict__ W,
    const float* __restrict__ bias,
    const float* __restrict__ bnscale,
    const float* __restrict__ bnshift,
    unsigned short* __restrict__ Y,
    float* __restrict__ osum,
    float* __restrict__ osq)
{
  __shared__ unsigned short As[128*64];   // 16 KB, XOR-swizzled 16B chunks
  __shared__ unsigned short Bs[256*64];   // 32 KB
  __shared__ float lsc[256], lsh[256];
  const int tid  = threadIdx.x;
  const int lane = tid & 63;
  const int wave = tid >> 6;
  const size_t mbase = (size_t)blockIdx.x * 128;
  if constexpr (BNRELU){ lsc[tid] = bnscale[tid]; lsh[tid] = bnshift[tid]; }
  f32x4 acc[8][4];
  #pragma unroll
  for (int m2 = 0; m2 < 8; ++m2)
    #pragma unroll
    for (int n2 = 0; n2 < 4; ++n2) acc[m2][n2] = f32x4{0.f,0.f,0.f,0.f};
  __syncthreads();

  for (int k0 = 0; k0 < KDIM; k0 += 64){
    if (k0) __syncthreads();
    // stage A: 128 rows x 8 chunks(16B) = 1024 chunks, 4/thread
    #pragma unroll
    for (int i = 0; i < 4; ++i){
      int cid = tid + 256*i;
      int row = cid >> 3, c8 = cid & 7;
      short8 v = *reinterpret_cast<const short8*>(A + (mbase+row)*KDIM + k0 + c8*8);
      if constexpr (BNRELU){
        #pragma unroll
        for (int j = 0; j < 8; ++j){
          int kc = k0 + c8*8 + j;
          float f = bf2f((unsigned short)v[j]);
          f = fmaxf(__fmaf_rn(f, lsc[kc], lsh[kc]), 0.0f);
          v[j] = (short)f2bf(f);
        }
      }
      *reinterpret_cast<short8*>(reinterpret_cast<char*>(As) + row*128 + ((c8 ^ (row&7)) << 4)) = v;
    }
    // stage B (weights): 256 rows x 8 chunks = 2048 chunks, 8/thread
    #pragma unroll
    for (int i = 0; i < 8; ++i){
      int cid = tid + 256*i;
      int row = cid >> 3, c8 = cid & 7;
      short8 v = *reinterpret_cast<const short8*>(W + (size_t)row*KDIM + k0 + c8*8);
      *reinterpret_cast<short8*>(reinterpret_cast<char*>(Bs) + row*128 + ((c8 ^ (row&7)) << 4)) = v;
    }
    __syncthreads();
    #pragma unroll
    for (int kk = 0; kk < 2; ++kk){
      short8 af[8], bv[4];
      #pragma unroll
      for (int m2 = 0; m2 < 8; ++m2){
        int row = m2*16 + (lane & 15);
        int c8  = kk*4 + (lane >> 4);
        af[m2] = *reinterpret_cast<const short8*>(reinterpret_cast<char*>(As) + row*128 + ((c8 ^ (row&7)) << 4));
      }
      #pragma unroll
      for (int n2 = 0; n2 < 4; ++n2){
        int row = wave*64 + n2*16 + (lane & 15);
        int c8  = kk*4 + (lane >> 4);
        bv[n2] = *reinterpret_cast<const short8*>(reinterpret_cast<char*>(Bs) + row*128 + ((c8 ^ (row&7)) << 4));
      }
      #pragma unroll
      for (int m2 = 0; m2 < 8; ++m2)
        #pragma unroll
        for (int n2 = 0; n2 < 4; ++n2)
          acc[m2][n2] = __builtin_amdgcn_mfma_f32_16x16x32_bf16(af[m2], bv[n2], acc[m2][n2], 0, 0, 0);
    }
  }

  // epilogue: C/D layout col = lane&15, row = (lane>>4)*4 + j  [m89-verified]
  const int colg0 = wave*64;
  float spart[4] = {0,0,0,0}, qpart[4] = {0,0,0,0};
  #pragma unroll
  for (int m2 = 0; m2 < 8; ++m2){
    #pragma unroll
    for (int n2 = 0; n2 < 4; ++n2){
      const int gc  = colg0 + n2*16 + (lane & 15);
      const float bvv = bias[gc];
      #pragma unroll
      for (int j = 0; j < 4; ++j){
        float yv = acc[m2][n2][j] + bvv;
        size_t gr = mbase + m2*16 + (lane>>4)*4 + j;
        Y[gr*256 + gc] = f2bf(yv);
        spart[n2] += yv;
        qpart[n2] = __fmaf_rn(yv, yv, qpart[n2]);
      }
    }
  }
  #pragma unroll
  for (int n2 = 0; n2 < 4; ++n2){
    float s = spart[n2], q = qpart[n2];
    s += __shfl_xor(s, 16); q += __shfl_xor(q, 16);
    s += __shfl_xor(s, 32); q += __shfl_xor(q, 32);
    if (lane < 16){
      int gc = colg0 + n2*16 + lane;
      atomicAdd(&osum[gc], s);
      atomicAdd(&osq[gc], q);
    }
  }
}

// ------------- BN finalize: scale/shift from sums -------------
__global__ void bnfin_kernel(const float* __restrict__ ss, const float* __restrict__ sq,
    const float* __restrict__ g, const float* __restrict__ bt,
    float* __restrict__ sc, float* __restrict__ sh)
{
  int c = threadIdx.x;
  float mean = ss[c] * (1.0f/65536.0f);
  float var  = sq[c] * (1.0f/65536.0f) - mean*mean;   // biased (torch default)
  float s = g[c] / sqrtf(var + 1e-5f);
  sc[c] = s;
  sh[c] = __fmaf_rn(-mean, s, bt[c]);
}

// ------------- final BN1 + ReLU -> fp32 out -------------
__global__ __launch_bounds__(256) void apply_kernel(
    const unsigned short* __restrict__ y,
    const float* __restrict__ sc, const float* __restrict__ sh,
    float* __restrict__ out)
{
  const int t = blockIdx.x*256 + threadIdx.x;
  const size_t base = (size_t)t * 8;
  const int c0 = (int)(base & 255);
  short8 v = *reinterpret_cast<const short8*>(y + base);
  float r[8];
  #pragma unroll
  for (int j = 0; j < 8; ++j){
    float f = bf2f((unsigned short)v[j]);
    f = __fmaf_rn(f, sc[c0+j], sh[c0+j]);
    r[j] = fmaxf(f, 0.0f);
  }
  float4 o0, o1;
  o0.x=r[0]; o0.y=r[1]; o0.z=r[2]; o0.w=r[3];
  o1.x=r[4]; o1.y=r[5]; o1.z=r[6]; o1.w=r[7];
  *reinterpret_cast<float4*>(out + base)     = o0;
  *reinterpret_cast<float4*>(out + base + 4) = o1;
}

// ---------------- workspace layout ----------------
constexpr size_t WS_STATS = 0;                                  // 4*256 f32
constexpr size_t WS_SCALE = 4096;                               // 4*256 f32
constexpr size_t WS_W0B   = 8192;                               // 98304 bf16
constexpr size_t WS_W1B   = WS_W0B + 196608;                    // 65536 bf16
constexpr size_t WS_KW    = WS_W1B + 131072;                    // M*3 f32
constexpr size_t WS_KI    = WS_KW + 786432;                     // M*3 i32
constexpr size_t WS_SKEY  = WS_KI + 786432;                     // B*Sn float4 (256KB)
constexpr size_t WS_X     = 4194304;                            // M*384 bf16 (50.3 MB)
constexpr size_t WS_Y0    = WS_X + (size_t)MTOT*CINn*2;         // M*256 bf16 (33.5 MB)
// Y1 reuses the X region (X dead after GEMM0). Peak ws ~ 88 MB.

extern "C" void kernel_launch(void* const* d_in, const int* in_sizes, int n_in,
                              void* d_out, int out_size, void* d_ws, size_t ws_size,
                              hipStream_t stream)
{
  const float* sxyz  = (const float*)d_in[0];
  const float* sfeat = (const float*)d_in[1];
  const float* oxyz  = (const float*)d_in[2];
  const float* ofeat = (const float*)d_in[3];
  const float* w0    = (const float*)d_in[4];
  const float* b0    = (const float*)d_in[5];
  const float* g0    = (const float*)d_in[6];
  const float* bt0   = (const float*)d_in[7];
  const float* w1    = (const float*)d_in[8];
  const float* b1    = (const float*)d_in[9];
  const float* g1    = (const float*)d_in[10];
  const float* bt1   = (const float*)d_in[11];
  // d_in[12] = k (always 3, hard-coded)

  char* ws = (char*)d_ws;
  float* stats  = (float*)(ws + WS_STATS);   // sum0,ssq0,sum1,ssq1
  float* scales = (float*)(ws + WS_SCALE);   // scale0,shift0,scale1,shift1
  unsigned short* w0b = (unsigned short*)(ws + WS_W0B);
  unsigned short* w1b = (unsigned short*)(ws + WS_W1B);
  float* kw = (float*)(ws + WS_KW);
  int*   ki = (int*)(ws + WS_KI);
  float4* skey = (float4*)(ws + WS_SKEY);
  unsigned short* X  = (unsigned short*)(ws + WS_X);
  unsigned short* Y0 = (unsigned short*)(ws + WS_Y0);
  unsigned short* Y1 = (unsigned short*)(ws + WS_X);   // reuse

  hipMemsetAsync(stats, 0, 4*256*sizeof(float), stream);
  cvtw_kernel<<<640, 256, 0, stream>>>(w0, w1, w0b, w1b);
  skey_kernel<<<(Bn*Sn)/256, 256, 0, stream>>>(sxyz, skey);
  knn_kernel<<<512, 512, 0, stream>>>(skey, oxyz, kw, ki);
  interp_kernel<<<MTOT/16, 256, 0, stream>>>(sfeat, ofeat, kw, ki, X);
  gemm_kernel<CINn, false><<<MTOT/128, 256, 0, stream>>>(
      X, w0b, b0, nullptr, nullptr, Y0, stats, stats + 256);
  bnfin_kernel<<<1, 256, 0, stream>>>(stats, stats + 256, g0, bt0, scales, scales + 256);
  gemm_kernel<256, true><<<MTOT/128, 256, 0, stream>>>(
      Y0, w1b, b1, scales, scales + 256, Y1, stats + 512, stats + 768);
  bnfin_kernel<<<1, 256, 0, stream>>>(stats + 512, stats + 768, g1, bt1, scales + 512, scales + 768);
  apply_kernel<<<(MTOT*256)/(256*8), 256, 0, stream>>>(Y1, scales + 512, scales + 768, (float*)d_out);
}

// Round 5
// 422.131 us; speedup vs baseline: 1.5107x; 1.2815x over previous
//
#include <hip/hip_runtime.h>
#include <hip/hip_bf16.h>
#include <cstdint>
#include <cstddef>

// Problem constants (fixed shapes)
#define Bn   4
#define Sn   4096
#define Nn   16384
#define CSn  256
#define COn  128
#define CINn 384
#define MTOT 65536   // B*N

using short8 = short __attribute__((ext_vector_type(8)));
using f32x4  = float __attribute__((ext_vector_type(4)));

static __device__ __forceinline__ float bf2f(unsigned short u){
  unsigned int x = ((unsigned int)u) << 16;
  return __builtin_bit_cast(float, x);
}
static __device__ __forceinline__ unsigned short f2bf(float f){
  unsigned int x = __builtin_bit_cast(unsigned int, f);
  x += 0x7fffu + ((x >> 16) & 1u);   // RNE (no NaN handling needed; data finite)
  return (unsigned short)(x >> 16);
}

// ---------------- KNN ----------------
static __device__ __forceinline__ void top3_insert(float d, int s,
    float& d0, float& d1, float& d2, int& i0, int& i1, int& i2){
  if (d < d2){
    if (d < d1){
      d2 = d1; i2 = i1;
      if (d < d0){ d1 = d0; i1 = i0; d0 = d; i0 = s; }
      else       { d1 = d;  i1 = s; }
    } else { d2 = d; i2 = s; }
  }
}

// precompute sampled keys (x,y,z,||s||^2) to global — L2 resident (64KB/batch)
__global__ __launch_bounds__(256) void skey_kernel(
    const float* __restrict__ sxyz, float4* __restrict__ skey)
{
  const int i = blockIdx.x*256 + threadIdx.x;      // 0 .. B*Sn-1
  float x = sxyz[(size_t)i*3+0], y = sxyz[(size_t)i*3+1], z = sxyz[(size_t)i*3+2];
  float ssv = __fadd_rn(__fadd_rn(__fmul_rn(x,x), __fmul_rn(y,y)), __fmul_rn(z,z));
  skey[i] = make_float4(x, y, z, ssv);
}

// 1024 blocks x 256 threads (4 waves). Block = 64 queries (lane = query);
// wave w scans contiguous S-quarter [w*1024,(w+1)*1024). Each wave self-stages
// its quarter into a wave-PRIVATE double-buffered LDS region (2 x 4KB chunks),
// no barriers in the main loop. Async-split staging: next chunk's 4 coalesced
// dwordx4 loads issue BEFORE scanning current chunk (scan = ~7000 cyc hides
// VMEM); ds_write lands after. Scan reads are wave-uniform ds_read_b128 =
// broadcast, conflict-free.
// Distance form matches reference: fma(-2, q.s, ||q||^2 + ||s||^2).
// Merge: ascending wave order, strict '<' => top_k tie-break preserved.
__global__ __launch_bounds__(256) void knn_kernel(
    const float4* __restrict__ skey, const float* __restrict__ oxyz,
    float* __restrict__ kw, int* __restrict__ ki)
{
  __shared__ float4 buf[4][2][256];   // 32 KB: wave-private double buffers
  __shared__ float  md[4][64][3];
  __shared__ int    mi[4][64][3];
  const int b    = blockIdx.x >> 8;      // 256 blocks per batch
  const int qblk = blockIdx.x & 255;
  const int lane = threadIdx.x & 63;
  const int wave = threadIdx.x >> 6;     // 0..3 = S-quarter
  const int n    = qblk*64 + lane;
  const float* op = oxyz + ((size_t)b*Nn + n)*3;
  const float px = op[0], py = op[1], pz = op[2];
  const float qq = __fadd_rn(__fadd_rn(__fmul_rn(px,px), __fmul_rn(py,py)), __fmul_rn(pz,pz));

  const float4* src = skey + (size_t)b*Sn + wave*1024;   // this wave's quarter

  // prologue: stage chunk 0
  float4 p0 = src[lane], p1 = src[lane+64], p2 = src[lane+128], p3 = src[lane+192];
  buf[wave][0][lane]     = p0;
  buf[wave][0][lane+64]  = p1;
  buf[wave][0][lane+128] = p2;
  buf[wave][0][lane+192] = p3;

  float d0 = 3.4e38f, d1 = 3.4e38f, d2 = 3.4e38f;
  int   i0 = 0, i1 = 0, i2 = 0;
  int cur = 0;
  for (int c = 0; c < 4; ++c){
    if (c < 3){                          // issue next chunk's loads EARLY
      const float4* s2 = src + (c+1)*256;
      p0 = s2[lane]; p1 = s2[lane+64]; p2 = s2[lane+128]; p3 = s2[lane+192];
    }
    const int sb = wave*1024 + c*256;
    #pragma unroll 4
    for (int i = 0; i < 256; ++i){       // broadcast ds_read_b128 per point
      float4 kv = buf[wave][cur][i];
      float dot = __fmaf_rn(pz, kv.z, __fmaf_rn(py, kv.y, __fmul_rn(px, kv.x)));
      float d   = __fmaf_rn(-2.0f, dot, __fadd_rn(qq, kv.w));
      top3_insert(d, sb + i, d0, d1, d2, i0, i1, i2);
    }
    if (c < 3){                          // write next chunk AFTER the scan
      int nxt = cur ^ 1;
      buf[wave][nxt][lane]     = p0;
      buf[wave][nxt][lane+64]  = p1;
      buf[wave][nxt][lane+128] = p2;
      buf[wave][nxt][lane+192] = p3;
      cur = nxt;
    }
  }

  md[wave][lane][0]=d0; md[wave][lane][1]=d1; md[wave][lane][2]=d2;
  mi[wave][lane][0]=i0; mi[wave][lane][1]=i1; mi[wave][lane][2]=i2;
  __syncthreads();
  if (threadIdx.x < 64){
    float e0=3.4e38f, e1=3.4e38f, e2=3.4e38f;
    int   j0=0, j1=0, j2=0;
    #pragma unroll
    for (int w = 0; w < 4; ++w){         // ascending quarters: tie-break safe
      top3_insert(md[w][lane][0], mi[w][lane][0], e0,e1,e2, j0,j1,j2);
      top3_insert(md[w][lane][1], mi[w][lane][1], e0,e1,e2, j0,j1,j2);
      top3_insert(md[w][lane][2], mi[w][lane][2], e0,e1,e2, j0,j1,j2);
    }
    float wa = 1.0f/(e0+1e-8f), wb = 1.0f/(e1+1e-8f), wc = 1.0f/(e2+1e-8f);
    float sm = __fadd_rn(__fadd_rn(wa, wb), wc);
    size_t base = ((size_t)b*Nn + n)*3;
    kw[base+0] = wa/sm; kw[base+1] = wb/sm; kw[base+2] = wc/sm;
    ki[base+0] = j0;    ki[base+1] = j1;    ki[base+2] = j2;
  }
}

// ------------- interpolate + concat -> x [M][384] bf16 -------------
__global__ __launch_bounds__(256) void interp_kernel(
    const float* __restrict__ sfeat, const float* __restrict__ ofeat,
    const float* __restrict__ kw, const int* __restrict__ ki,
    unsigned short* __restrict__ X)
{
  const int c  = threadIdx.x;          // channel 0..255
  const int m0 = blockIdx.x * 16;      // 16 points per block
  for (int p = 0; p < 16; ++p){
    const int m = m0 + p;
    const int b = m >> 14;             // N = 16384
    const float w0v = kw[(size_t)m*3+0], w1v = kw[(size_t)m*3+1], w2v = kw[(size_t)m*3+2];
    const int   i0  = ki[(size_t)m*3+0], i1  = ki[(size_t)m*3+1], i2  = ki[(size_t)m*3+2];
    const float* sb = sfeat + (size_t)b * Sn * CSn;
    float v = __fmaf_rn(w2v, sb[(size_t)i2*CSn + c],
              __fmaf_rn(w1v, sb[(size_t)i1*CSn + c],
              __fmul_rn(w0v, sb[(size_t)i0*CSn + c])));
    X[(size_t)m*CINn + COn + c] = f2bf(v);
    if (c < COn) X[(size_t)m*CINn + c] = f2bf(ofeat[(size_t)m*COn + c]);
  }
}

// ------------- fp32 -> bf16 weight conversion -------------
__global__ __launch_bounds__(256) void cvtw_kernel(
    const float* __restrict__ w0, const float* __restrict__ w1,
    unsigned short* __restrict__ w0b, unsigned short* __restrict__ w1b)
{
  int i = blockIdx.x*256 + threadIdx.x;
  if (i < 256*384) w0b[i] = f2bf(w0[i]);
  int j = i - 256*384;
  if (j >= 0 && j < 256*256) w1b[j] = f2bf(w1[j]);
}

// ------------- GEMM: Y[M][256] = A[M][KDIM] @ W[256][KDIM]^T + bias ----------
// BM=128, BN=256 (full), BK=64. 4 waves, wave w owns cols [w*64, w*64+64).
// Optional prologue: A' = relu(A*scale[k] + shift[k]) (BN0+ReLU fused into GEMM1).
// Epilogue: bf16 store + per-channel sum/sumsq atomics for BN stats.
template<int KDIM, bool BNRELU>
__global__ __launch_bounds__(256) void gemm_kernel(
    const unsigned short* __restrict__ A,
    const unsigned short* __restrict__ W,
    const float* __restrict__ bias,
    const float* __restrict__ bnscale,
    const float* __restrict__ bnshift,
    unsigned short* __restrict__ Y,
    float* __restrict__ osum,
    float* __restrict__ osq)
{
  __shared__ unsigned short As[128*64];   // 16 KB, XOR-swizzled 16B chunks
  __shared__ unsigned short Bs[256*64];   // 32 KB
  __shared__ float lsc[256], lsh[256];
  const int tid  = threadIdx.x;
  const int lane = tid & 63;
  const int wave = tid >> 6;
  const size_t mbase = (size_t)blockIdx.x * 128;
  if constexpr (BNRELU){ lsc[tid] = bnscale[tid]; lsh[tid] = bnshift[tid]; }
  f32x4 acc[8][4];
  #pragma unroll
  for (int m2 = 0; m2 < 8; ++m2)
    #pragma unroll
    for (int n2 = 0; n2 < 4; ++n2) acc[m2][n2] = f32x4{0.f,0.f,0.f,0.f};
  __syncthreads();

  for (int k0 = 0; k0 < KDIM; k0 += 64){
    if (k0) __syncthreads();
    // stage A: 128 rows x 8 chunks(16B) = 1024 chunks, 4/thread
    #pragma unroll
    for (int i = 0; i < 4; ++i){
      int cid = tid + 256*i;
      int row = cid >> 3, c8 = cid & 7;
      short8 v = *reinterpret_cast<const short8*>(A + (mbase+row)*KDIM + k0 + c8*8);
      if constexpr (BNRELU){
        #pragma unroll
        for (int j = 0; j < 8; ++j){
          int kc = k0 + c8*8 + j;
          float f = bf2f((unsigned short)v[j]);
          f = fmaxf(__fmaf_rn(f, lsc[kc], lsh[kc]), 0.0f);
          v[j] = (short)f2bf(f);
        }
      }
      *reinterpret_cast<short8*>(reinterpret_cast<char*>(As) + row*128 + ((c8 ^ (row&7)) << 4)) = v;
    }
    // stage B (weights): 256 rows x 8 chunks = 2048 chunks, 8/thread
    #pragma unroll
    for (int i = 0; i < 8; ++i){
      int cid = tid + 256*i;
      int row = cid >> 3, c8 = cid & 7;
      short8 v = *reinterpret_cast<const short8*>(W + (size_t)row*KDIM + k0 + c8*8);
      *reinterpret_cast<short8*>(reinterpret_cast<char*>(Bs) + row*128 + ((c8 ^ (row&7)) << 4)) = v;
    }
    __syncthreads();
    #pragma unroll
    for (int kk = 0; kk < 2; ++kk){
      short8 af[8], bv[4];
      #pragma unroll
      for (int m2 = 0; m2 < 8; ++m2){
        int row = m2*16 + (lane & 15);
        int c8  = kk*4 + (lane >> 4);
        af[m2] = *reinterpret_cast<const short8*>(reinterpret_cast<char*>(As) + row*128 + ((c8 ^ (row&7)) << 4));
      }
      #pragma unroll
      for (int n2 = 0; n2 < 4; ++n2){
        int row = wave*64 + n2*16 + (lane & 15);
        int c8  = kk*4 + (lane >> 4);
        bv[n2] = *reinterpret_cast<const short8*>(reinterpret_cast<char*>(Bs) + row*128 + ((c8 ^ (row&7)) << 4));
      }
      #pragma unroll
      for (int m2 = 0; m2 < 8; ++m2)
        #pragma unroll
        for (int n2 = 0; n2 < 4; ++n2)
          acc[m2][n2] = __builtin_amdgcn_mfma_f32_16x16x32_bf16(af[m2], bv[n2], acc[m2][n2], 0, 0, 0);
    }
  }

  // epilogue: C/D layout col = lane&15, row = (lane>>4)*4 + j  [m89-verified]
  const int colg0 = wave*64;
  float spart[4] = {0,0,0,0}, qpart[4] = {0,0,0,0};
  #pragma unroll
  for (int m2 = 0; m2 < 8; ++m2){
    #pragma unroll
    for (int n2 = 0; n2 < 4; ++n2){
      const int gc  = colg0 + n2*16 + (lane & 15);
      const float bvv = bias[gc];
      #pragma unroll
      for (int j = 0; j < 4; ++j){
        float yv = acc[m2][n2][j] + bvv;
        size_t gr = mbase + m2*16 + (lane>>4)*4 + j;
        Y[gr*256 + gc] = f2bf(yv);
        spart[n2] += yv;
        qpart[n2] = __fmaf_rn(yv, yv, qpart[n2]);
      }
    }
  }
  #pragma unroll
  for (int n2 = 0; n2 < 4; ++n2){
    float s = spart[n2], q = qpart[n2];
    s += __shfl_xor(s, 16); q += __shfl_xor(q, 16);
    s += __shfl_xor(s, 32); q += __shfl_xor(q, 32);
    if (lane < 16){
      int gc = colg0 + n2*16 + lane;
      atomicAdd(&osum[gc], s);
      atomicAdd(&osq[gc], q);
    }
  }
}

// ------------- BN finalize: scale/shift from sums -------------
__global__ void bnfin_kernel(const float* __restrict__ ss, const float* __restrict__ sq,
    const float* __restrict__ g, const float* __restrict__ bt,
    float* __restrict__ sc, float* __restrict__ sh)
{
  int c = threadIdx.x;
  float mean = ss[c] * (1.0f/65536.0f);
  float var  = sq[c] * (1.0f/65536.0f) - mean*mean;   // biased (torch default)
  float s = g[c] / sqrtf(var + 1e-5f);
  sc[c] = s;
  sh[c] = __fmaf_rn(-mean, s, bt[c]);
}

// ------------- final BN1 + ReLU -> fp32 out -------------
__global__ __launch_bounds__(256) void apply_kernel(
    const unsigned short* __restrict__ y,
    const float* __restrict__ sc, const float* __restrict__ sh,
    float* __restrict__ out)
{
  const int t = blockIdx.x*256 + threadIdx.x;
  const size_t base = (size_t)t * 8;
  const int c0 = (int)(base & 255);
  short8 v = *reinterpret_cast<const short8*>(y + base);
  float r[8];
  #pragma unroll
  for (int j = 0; j < 8; ++j){
    float f = bf2f((unsigned short)v[j]);
    f = __fmaf_rn(f, sc[c0+j], sh[c0+j]);
    r[j] = fmaxf(f, 0.0f);
  }
  float4 o0, o1;
  o0.x=r[0]; o0.y=r[1]; o0.z=r[2]; o0.w=r[3];
  o1.x=r[4]; o1.y=r[5]; o1.z=r[6]; o1.w=r[7];
  *reinterpret_cast<float4*>(out + base)     = o0;
  *reinterpret_cast<float4*>(out + base + 4) = o1;
}

// ---------------- workspace layout ----------------
constexpr size_t WS_STATS = 0;                                  // 4*256 f32
constexpr size_t WS_SCALE = 4096;                               // 4*256 f32
constexpr size_t WS_W0B   = 8192;                               // 98304 bf16
constexpr size_t WS_W1B   = WS_W0B + 196608;                    // 65536 bf16
constexpr size_t WS_KW    = WS_W1B + 131072;                    // M*3 f32
constexpr size_t WS_KI    = WS_KW + 786432;                     // M*3 i32
constexpr size_t WS_SKEY  = WS_KI + 786432;                     // B*Sn float4 (256KB)
constexpr size_t WS_X     = 4194304;                            // M*384 bf16 (50.3 MB)
constexpr size_t WS_Y0    = WS_X + (size_t)MTOT*CINn*2;         // M*256 bf16 (33.5 MB)
// Y1 reuses the X region (X dead after GEMM0). Peak ws ~ 88 MB.

extern "C" void kernel_launch(void* const* d_in, const int* in_sizes, int n_in,
                              void* d_out, int out_size, void* d_ws, size_t ws_size,
                              hipStream_t stream)
{
  const float* sxyz  = (const float*)d_in[0];
  const float* sfeat = (const float*)d_in[1];
  const float* oxyz  = (const float*)d_in[2];
  const float* ofeat = (const float*)d_in[3];
  const float* w0    = (const float*)d_in[4];
  const float* b0    = (const float*)d_in[5];
  const float* g0    = (const float*)d_in[6];
  const float* bt0   = (const float*)d_in[7];
  const float* w1    = (const float*)d_in[8];
  const float* b1    = (const float*)d_in[9];
  const float* g1    = (const float*)d_in[10];
  const float* bt1   = (const float*)d_in[11];
  // d_in[12] = k (always 3, hard-coded)

  char* ws = (char*)d_ws;
  float* stats  = (float*)(ws + WS_STATS);   // sum0,ssq0,sum1,ssq1
  float* scales = (float*)(ws + WS_SCALE);   // scale0,shift0,scale1,shift1
  unsigned short* w0b = (unsigned short*)(ws + WS_W0B);
  unsigned short* w1b = (unsigned short*)(ws + WS_W1B);
  float* kw = (float*)(ws + WS_KW);
  int*   ki = (int*)(ws + WS_KI);
  float4* skey = (float4*)(ws + WS_SKEY);
  unsigned short* X  = (unsigned short*)(ws + WS_X);
  unsigned short* Y0 = (unsigned short*)(ws + WS_Y0);
  unsigned short* Y1 = (unsigned short*)(ws + WS_X);   // reuse

  hipMemsetAsync(stats, 0, 4*256*sizeof(float), stream);
  cvtw_kernel<<<640, 256, 0, stream>>>(w0, w1, w0b, w1b);
  skey_kernel<<<(Bn*Sn)/256, 256, 0, stream>>>(sxyz, skey);
  knn_kernel<<<1024, 256, 0, stream>>>(skey, oxyz, kw, ki);
  interp_kernel<<<MTOT/16, 256, 0, stream>>>(sfeat, ofeat, kw, ki, X);
  gemm_kernel<CINn, false><<<MTOT/128, 256, 0, stream>>>(
      X, w0b, b0, nullptr, nullptr, Y0, stats, stats + 256);
  bnfin_kernel<<<1, 256, 0, stream>>>(stats, stats + 256, g0, bt0, scales, scales + 256);
  gemm_kernel<256, true><<<MTOT/128, 256, 0, stream>>>(
      Y0, w1b, b1, scales, scales + 256, Y1, stats + 512, stats + 768);
  bnfin_kernel<<<1, 256, 0, stream>>>(stats + 512, stats + 768, g1, bt1, scales + 512, scales + 768);
  apply_kernel<<<(MTOT*256)/(256*8), 256, 0, stream>>>(Y1, scales + 512, scales + 768, (float*)d_out);
}

// Round 6
// 298.581 us; speedup vs baseline: 2.1358x; 1.4138x over previous
//
#include <hip/hip_runtime.h>
#include <hip/hip_bf16.h>
#include <cstdint>
#include <cstddef>

// Problem constants (fixed shapes)
#define Bn   4
#define Sn   4096
#define Nn   16384
#define CSn  256
#define COn  128
#define CINn 384
#define MTOT 65536   // B*N

using short8 = short __attribute__((ext_vector_type(8)));
using f32x4  = float __attribute__((ext_vector_type(4)));

static __device__ __forceinline__ float bf2f(unsigned short u){
  unsigned int x = ((unsigned int)u) << 16;
  return __builtin_bit_cast(float, x);
}
static __device__ __forceinline__ unsigned short f2bf(float f){
  unsigned int x = __builtin_bit_cast(unsigned int, f);
  x += 0x7fffu + ((x >> 16) & 1u);   // RNE (no NaN handling needed; data finite)
  return (unsigned short)(x >> 16);
}

// broadcast lane l's value to all lanes (result in SGPR)
static __device__ __forceinline__ float rl(float v, int l){
  return __builtin_bit_cast(float, __builtin_amdgcn_readlane(__builtin_bit_cast(int, v), l));
}

// ---------------- KNN ----------------
// branchy insert kept ONLY for the tiny LDS merge (128 threads, 12 values)
static __device__ __forceinline__ void top3_insert(float d, int s,
    float& d0, float& d1, float& d2, int& i0, int& i1, int& i2){
  if (d < d2){
    if (d < d1){
      d2 = d1; i2 = i1;
      if (d < d0){ d1 = d0; i1 = i0; d0 = d; i0 = s; }
      else       { d1 = d;  i1 = s; }
    } else { d2 = d; i2 = s; }
  }
}

// precompute sampled keys (x,y,z,||s||^2) to global — L2 resident (64KB/batch)
__global__ __launch_bounds__(256) void skey_kernel(
    const float* __restrict__ sxyz, float4* __restrict__ skey)
{
  const int i = blockIdx.x*256 + threadIdx.x;      // 0 .. B*Sn-1
  float x = sxyz[(size_t)i*3+0], y = sxyz[(size_t)i*3+1], z = sxyz[(size_t)i*3+2];
  float ssv = __fadd_rn(__fadd_rn(__fmul_rn(x,x), __fmul_rn(y,y)), __fmul_rn(z,z));
  skey[i] = make_float4(x, y, z, ssv);
}

// 1024 blocks x 256 threads (4 waves). Block = 64 queries (lane = query);
// wave w scans S-quarter [w*1024,(w+1)*1024) via an all-register systolic
// pattern: each lane loads ONE key float4 per 64-step super-iteration
// (coalesced), and the 64 steps broadcast lane j's key to the whole wave with
// v_readlane (literal lane index, fully unrolled) -> keys in SGPRs, no memory
// op in the inner loop. Top-3 maintenance is BRANCH-FREE:
//   d0'=min(d,d0), d1'=med3(d,d0,d1), d2'=med3(d,d1,d2) + cndmask indices.
// Strict '<' + ascending s order => reference top_k tie-break preserved.
// Distance form bit-matches reference: fma(-2, q.s, ||q||^2 + ||s||^2).
__global__ __launch_bounds__(256) void knn_kernel(
    const float4* __restrict__ skey, const float* __restrict__ oxyz,
    float* __restrict__ kw, int* __restrict__ ki)
{
  __shared__ float md[4][64][3];
  __shared__ int   mi[4][64][3];
  const int b    = blockIdx.x >> 8;      // 256 blocks per batch
  const int qblk = blockIdx.x & 255;
  const int lane = threadIdx.x & 63;
  const int wave = threadIdx.x >> 6;     // 0..3 = S-quarter
  const int n    = qblk*64 + lane;
  const float* op = oxyz + ((size_t)b*Nn + n)*3;
  const float px = op[0], py = op[1], pz = op[2];
  const float qq = __fadd_rn(__fadd_rn(__fmul_rn(px,px), __fmul_rn(py,py)), __fmul_rn(pz,pz));

  const float4* src = skey + (size_t)b*Sn + wave*1024;   // this wave's quarter

  float4 cur = src[lane];                // key owned by this lane (64/superiter)
  float d0 = 3.4e38f, d1 = 3.4e38f, d2 = 3.4e38f;
  int   i0 = 0, i1 = 0, i2 = 0;

  for (int t = 0; t < 16; ++t){
    float4 nxt = src[((t+1)&15)*64 + lane];   // prefetch (wraps harmlessly on last)
    const int sb = wave*1024 + t*64;
    #pragma unroll
    for (int j = 0; j < 64; ++j){
      const float kx = rl(cur.x, j), ky = rl(cur.y, j);
      const float kz = rl(cur.z, j), ss = rl(cur.w, j);
      float dot = __fmaf_rn(pz, kz, __fmaf_rn(py, ky, __fmul_rn(px, kx)));
      float dd  = __fmaf_rn(-2.0f, dot, __fadd_rn(qq, ss));
      const int sidx = sb + j;
      const bool c0 = dd < d0, c1 = dd < d1, c2 = dd < d2;
      const float od0 = d0, od1 = d1;
      d0 = fminf(dd, od0);
      d1 = __builtin_amdgcn_fmed3f(dd, od0, od1);
      d2 = __builtin_amdgcn_fmed3f(dd, od1, d2);
      i2 = c2 ? (c1 ? i1 : sidx) : i2;    // old i1
      i1 = c1 ? (c0 ? i0 : sidx) : i1;    // old i0
      i0 = c0 ? sidx : i0;
    }
    cur = nxt;
  }

  md[wave][lane][0]=d0; md[wave][lane][1]=d1; md[wave][lane][2]=d2;
  mi[wave][lane][0]=i0; mi[wave][lane][1]=i1; mi[wave][lane][2]=i2;
  __syncthreads();
  if (threadIdx.x < 64){
    float e0=3.4e38f, e1=3.4e38f, e2=3.4e38f;
    int   j0=0, j1=0, j2=0;
    #pragma unroll
    for (int w = 0; w < 4; ++w){         // ascending quarters: tie-break safe
      top3_insert(md[w][lane][0], mi[w][lane][0], e0,e1,e2, j0,j1,j2);
      top3_insert(md[w][lane][1], mi[w][lane][1], e0,e1,e2, j0,j1,j2);
      top3_insert(md[w][lane][2], mi[w][lane][2], e0,e1,e2, j0,j1,j2);
    }
    float wa = 1.0f/(e0+1e-8f), wb = 1.0f/(e1+1e-8f), wc = 1.0f/(e2+1e-8f);
    float sm = __fadd_rn(__fadd_rn(wa, wb), wc);
    size_t base = ((size_t)b*Nn + n)*3;
    kw[base+0] = wa/sm; kw[base+1] = wb/sm; kw[base+2] = wc/sm;
    ki[base+0] = j0;    ki[base+1] = j1;    ki[base+2] = j2;
  }
}

// ------------- interpolate + concat -> x [M][384] bf16 -------------
__global__ __launch_bounds__(256) void interp_kernel(
    const float* __restrict__ sfeat, const float* __restrict__ ofeat,
    const float* __restrict__ kw, const int* __restrict__ ki,
    unsigned short* __restrict__ X)
{
  const int c  = threadIdx.x;          // channel 0..255
  const int m0 = blockIdx.x * 16;      // 16 points per block
  for (int p = 0; p < 16; ++p){
    const int m = m0 + p;
    const int b = m >> 14;             // N = 16384
    const float w0v = kw[(size_t)m*3+0], w1v = kw[(size_t)m*3+1], w2v = kw[(size_t)m*3+2];
    const int   i0  = ki[(size_t)m*3+0], i1  = ki[(size_t)m*3+1], i2  = ki[(size_t)m*3+2];
    const float* sb = sfeat + (size_t)b * Sn * CSn;
    float v = __fmaf_rn(w2v, sb[(size_t)i2*CSn + c],
              __fmaf_rn(w1v, sb[(size_t)i1*CSn + c],
              __fmul_rn(w0v, sb[(size_t)i0*CSn + c])));
    X[(size_t)m*CINn + COn + c] = f2bf(v);
    if (c < COn) X[(size_t)m*CINn + c] = f2bf(ofeat[(size_t)m*COn + c]);
  }
}

// ------------- fp32 -> bf16 weight conversion -------------
__global__ __launch_bounds__(256) void cvtw_kernel(
    const float* __restrict__ w0, const float* __restrict__ w1,
    unsigned short* __restrict__ w0b, unsigned short* __restrict__ w1b)
{
  int i = blockIdx.x*256 + threadIdx.x;
  if (i < 256*384) w0b[i] = f2bf(w0[i]);
  int j = i - 256*384;
  if (j >= 0 && j < 256*256) w1b[j] = f2bf(w1[j]);
}

// ------------- GEMM: Y[M][256] = A[M][KDIM] @ W[256][KDIM]^T + bias ----------
// BM=128, BN=256 (full), BK=64. 4 waves, wave w owns cols [w*64, w*64+64).
// Optional prologue: A' = relu(A*scale[k] + shift[k]) (BN0+ReLU fused into GEMM1).
// Epilogue: bf16 store + per-channel sum/sumsq atomics for BN stats.
template<int KDIM, bool BNRELU>
__global__ __launch_bounds__(256) void gemm_kernel(
    const unsigned short* __restrict__ A,
    const unsigned short* __restrict__ W,
    const float* __restrict__ bias,
    const float* __restrict__ bnscale,
    const float* __restrict__ bnshift,
    unsigned short* __restrict__ Y,
    float* __restrict__ osum,
    float* __restrict__ osq)
{
  __shared__ unsigned short As[128*64];   // 16 KB, XOR-swizzled 16B chunks
  __shared__ unsigned short Bs[256*64];   // 32 KB
  __shared__ float lsc[256], lsh[256];
  const int tid  = threadIdx.x;
  const int lane = tid & 63;
  const int wave = tid >> 6;
  const size_t mbase = (size_t)blockIdx.x * 128;
  if constexpr (BNRELU){ lsc[tid] = bnscale[tid]; lsh[tid] = bnshift[tid]; }
  f32x4 acc[8][4];
  #pragma unroll
  for (int m2 = 0; m2 < 8; ++m2)
    #pragma unroll
    for (int n2 = 0; n2 < 4; ++n2) acc[m2][n2] = f32x4{0.f,0.f,0.f,0.f};
  __syncthreads();

  for (int k0 = 0; k0 < KDIM; k0 += 64){
    if (k0) __syncthreads();
    // stage A: 128 rows x 8 chunks(16B) = 1024 chunks, 4/thread
    #pragma unroll
    for (int i = 0; i < 4; ++i){
      int cid = tid + 256*i;
      int row = cid >> 3, c8 = cid & 7;
      short8 v = *reinterpret_cast<const short8*>(A + (mbase+row)*KDIM + k0 + c8*8);
      if constexpr (BNRELU){
        #pragma unroll
        for (int j = 0; j < 8; ++j){
          int kc = k0 + c8*8 + j;
          float f = bf2f((unsigned short)v[j]);
          f = fmaxf(__fmaf_rn(f, lsc[kc], lsh[kc]), 0.0f);
          v[j] = (short)f2bf(f);
        }
      }
      *reinterpret_cast<short8*>(reinterpret_cast<char*>(As) + row*128 + ((c8 ^ (row&7)) << 4)) = v;
    }
    // stage B (weights): 256 rows x 8 chunks = 2048 chunks, 8/thread
    #pragma unroll
    for (int i = 0; i < 8; ++i){
      int cid = tid + 256*i;
      int row = cid >> 3, c8 = cid & 7;
      short8 v = *reinterpret_cast<const short8*>(W + (size_t)row*KDIM + k0 + c8*8);
      *reinterpret_cast<short8*>(reinterpret_cast<char*>(Bs) + row*128 + ((c8 ^ (row&7)) << 4)) = v;
    }
    __syncthreads();
    #pragma unroll
    for (int kk = 0; kk < 2; ++kk){
      short8 af[8], bv[4];
      #pragma unroll
      for (int m2 = 0; m2 < 8; ++m2){
        int row = m2*16 + (lane & 15);
        int c8  = kk*4 + (lane >> 4);
        af[m2] = *reinterpret_cast<const short8*>(reinterpret_cast<char*>(As) + row*128 + ((c8 ^ (row&7)) << 4));
      }
      #pragma unroll
      for (int n2 = 0; n2 < 4; ++n2){
        int row = wave*64 + n2*16 + (lane & 15);
        int c8  = kk*4 + (lane >> 4);
        bv[n2] = *reinterpret_cast<const short8*>(reinterpret_cast<char*>(Bs) + row*128 + ((c8 ^ (row&7)) << 4));
      }
      #pragma unroll
      for (int m2 = 0; m2 < 8; ++m2)
        #pragma unroll
        for (int n2 = 0; n2 < 4; ++n2)
          acc[m2][n2] = __builtin_amdgcn_mfma_f32_16x16x32_bf16(af[m2], bv[n2], acc[m2][n2], 0, 0, 0);
    }
  }

  // epilogue: C/D layout col = lane&15, row = (lane>>4)*4 + j  [m89-verified]
  const int colg0 = wave*64;
  float spart[4] = {0,0,0,0}, qpart[4] = {0,0,0,0};
  #pragma unroll
  for (int m2 = 0; m2 < 8; ++m2){
    #pragma unroll
    for (int n2 = 0; n2 < 4; ++n2){
      const int gc  = colg0 + n2*16 + (lane & 15);
      const float bvv = bias[gc];
      #pragma unroll
      for (int j = 0; j < 4; ++j){
        float yv = acc[m2][n2][j] + bvv;
        size_t gr = mbase + m2*16 + (lane>>4)*4 + j;
        Y[gr*256 + gc] = f2bf(yv);
        spart[n2] += yv;
        qpart[n2] = __fmaf_rn(yv, yv, qpart[n2]);
      }
    }
  }
  #pragma unroll
  for (int n2 = 0; n2 < 4; ++n2){
    float s = spart[n2], q = qpart[n2];
    s += __shfl_xor(s, 16); q += __shfl_xor(q, 16);
    s += __shfl_xor(s, 32); q += __shfl_xor(q, 32);
    if (lane < 16){
      int gc = colg0 + n2*16 + lane;
      atomicAdd(&osum[gc], s);
      atomicAdd(&osq[gc], q);
    }
  }
}

// ------------- BN finalize: scale/shift from sums -------------
__global__ void bnfin_kernel(const float* __restrict__ ss, const float* __restrict__ sq,
    const float* __restrict__ g, const float* __restrict__ bt,
    float* __restrict__ sc, float* __restrict__ sh)
{
  int c = threadIdx.x;
  float mean = ss[c] * (1.0f/65536.0f);
  float var  = sq[c] * (1.0f/65536.0f) - mean*mean;   // biased (torch default)
  float s = g[c] / sqrtf(var + 1e-5f);
  sc[c] = s;
  sh[c] = __fmaf_rn(-mean, s, bt[c]);
}

// ------------- final BN1 + ReLU -> fp32 out -------------
__global__ __launch_bounds__(256) void apply_kernel(
    const unsigned short* __restrict__ y,
    const float* __restrict__ sc, const float* __restrict__ sh,
    float* __restrict__ out)
{
  const int t = blockIdx.x*256 + threadIdx.x;
  const size_t base = (size_t)t * 8;
  const int c0 = (int)(base & 255);
  short8 v = *reinterpret_cast<const short8*>(y + base);
  float r[8];
  #pragma unroll
  for (int j = 0; j < 8; ++j){
    float f = bf2f((unsigned short)v[j]);
    f = __fmaf_rn(f, sc[c0+j], sh[c0+j]);
    r[j] = fmaxf(f, 0.0f);
  }
  float4 o0, o1;
  o0.x=r[0]; o0.y=r[1]; o0.z=r[2]; o0.w=r[3];
  o1.x=r[4]; o1.y=r[5]; o1.z=r[6]; o1.w=r[7];
  *reinterpret_cast<float4*>(out + base)     = o0;
  *reinterpret_cast<float4*>(out + base + 4) = o1;
}

// ---------------- workspace layout ----------------
constexpr size_t WS_STATS = 0;                                  // 4*256 f32
constexpr size_t WS_SCALE = 4096;                               // 4*256 f32
constexpr size_t WS_W0B   = 8192;                               // 98304 bf16
constexpr size_t WS_W1B   = WS_W0B + 196608;                    // 65536 bf16
constexpr size_t WS_KW    = WS_W1B + 131072;                    // M*3 f32
constexpr size_t WS_KI    = WS_KW + 786432;                     // M*3 i32
constexpr size_t WS_SKEY  = WS_KI + 786432;                     // B*Sn float4 (256KB)
constexpr size_t WS_X     = 4194304;                            // M*384 bf16 (50.3 MB)
constexpr size_t WS_Y0    = WS_X + (size_t)MTOT*CINn*2;         // M*256 bf16 (33.5 MB)
// Y1 reuses the X region (X dead after GEMM0). Peak ws ~ 88 MB.

extern "C" void kernel_launch(void* const* d_in, const int* in_sizes, int n_in,
                              void* d_out, int out_size, void* d_ws, size_t ws_size,
                              hipStream_t stream)
{
  const float* sxyz  = (const float*)d_in[0];
  const float* sfeat = (const float*)d_in[1];
  const float* oxyz  = (const float*)d_in[2];
  const float* ofeat = (const float*)d_in[3];
  const float* w0    = (const float*)d_in[4];
  const float* b0    = (const float*)d_in[5];
  const float* g0    = (const float*)d_in[6];
  const float* bt0   = (const float*)d_in[7];
  const float* w1    = (const float*)d_in[8];
  const float* b1    = (const float*)d_in[9];
  const float* g1    = (const float*)d_in[10];
  const float* bt1   = (const float*)d_in[11];
  // d_in[12] = k (always 3, hard-coded)

  char* ws = (char*)d_ws;
  float* stats  = (float*)(ws + WS_STATS);   // sum0,ssq0,sum1,ssq1
  float* scales = (float*)(ws + WS_SCALE);   // scale0,shift0,scale1,shift1
  unsigned short* w0b = (unsigned short*)(ws + WS_W0B);
  unsigned short* w1b = (unsigned short*)(ws + WS_W1B);
  float* kw = (float*)(ws + WS_KW);
  int*   ki = (int*)(ws + WS_KI);
  float4* skey = (float4*)(ws + WS_SKEY);
  unsigned short* X  = (unsigned short*)(ws + WS_X);
  unsigned short* Y0 = (unsigned short*)(ws + WS_Y0);
  unsigned short* Y1 = (unsigned short*)(ws + WS_X);   // reuse

  hipMemsetAsync(stats, 0, 4*256*sizeof(float), stream);
  cvtw_kernel<<<640, 256, 0, stream>>>(w0, w1, w0b, w1b);
  skey_kernel<<<(Bn*Sn)/256, 256, 0, stream>>>(sxyz, skey);
  knn_kernel<<<1024, 256, 0, stream>>>(skey, oxyz, kw, ki);
  interp_kernel<<<MTOT/16, 256, 0, stream>>>(sfeat, ofeat, kw, ki, X);
  gemm_kernel<CINn, false><<<MTOT/128, 256, 0, stream>>>(
      X, w0b, b0, nullptr, nullptr, Y0, stats, stats + 256);
  bnfin_kernel<<<1, 256, 0, stream>>>(stats, stats + 256, g0, bt0, scales, scales + 256);
  gemm_kernel<256, true><<<MTOT/128, 256, 0, stream>>>(
      Y0, w1b, b1, scales, scales + 256, Y1, stats + 512, stats + 768);
  bnfin_kernel<<<1, 256, 0, stream>>>(stats + 512, stats + 768, g1, bt1, scales + 512, scales + 768);
  apply_kernel<<<(MTOT*256)/(256*8), 256, 0, stream>>>(Y1, scales + 512, scales + 768, (float*)d_out);
}